// Round 10
// baseline (571.645 us; speedup 1.0000x reference)
//
#include <hip/hip_runtime.h>
#include <hip/hip_bf16.h>

// ---------------------------------------------------------------------------
// CustomMultiheadAttention on MI355X (gfx950)
//   x = softmax((q Wq^T + bq)(k Wk^T + bk)^T / sqrt(64)) (v Wv^T + bv) Wo^T + bo
// Outputs (concat, fp32): x [4,2048,1024], attn [4,16,2048,2048]
//
// Round-9b (resubmit after infra failure): revert Vt2 production to the
// coalesced transpose kernel (now emitting the key-permuted layout;
// round-8's 2B-scatter epilogue was the regression). Keep pass1/pass2 split
// + single-b128 PV reads. NEW: per-wave q-register-blocking x2 — each wave
// holds Q frags for TWO q-tiles and issues 2 MFMAs per K/V fragment read,
// halving ds_read/staging/barriers per q-row.
// ---------------------------------------------------------------------------

typedef _Float16 h4 __attribute__((ext_vector_type(4)));
typedef _Float16 h8 __attribute__((ext_vector_type(8)));
typedef float f4 __attribute__((ext_vector_type(4)));

#define EMBED 1024
#define HEADS 16
#define HD 64
#define BB 4
#define SS 2048
#define MROWS (BB * SS) // 8192

#define GLD(src, dst)                                                                  \
  __builtin_amdgcn_global_load_lds((const __attribute__((address_space(1))) void*)(src), \
                                   (__attribute__((address_space(3))) void*)(dst), 16, 0, 0)

__device__ inline float fexp2(float x) {
  float r;
  asm("v_exp_f32 %0, %1" : "=v"(r) : "v"(x));
  return r;
}

// ---------------- fused casts fp32 -> fp16 ----------------
__global__ __launch_bounds__(256) void cast3_f32_f16(const float* __restrict__ a,
                                                     const float* __restrict__ b,
                                                     const float* __restrict__ c,
                                                     _Float16* __restrict__ oa,
                                                     _Float16* __restrict__ ob,
                                                     _Float16* __restrict__ oc, int n) {
  const float* in = blockIdx.y == 0 ? a : blockIdx.y == 1 ? b : c;
  _Float16* out = blockIdx.y == 0 ? oa : blockIdx.y == 1 ? ob : oc;
  int i = (blockIdx.x * 256 + threadIdx.x) * 4;
  if (i < n) {
    float4 v = *reinterpret_cast<const float4*>(in + i);
    h4 o = {(_Float16)v.x, (_Float16)v.y, (_Float16)v.z, (_Float16)v.w};
    *reinterpret_cast<h4*>(out + i) = o;
  }
}

__global__ __launch_bounds__(256) void cast4_f32_f16(const float* __restrict__ a,
                                                     const float* __restrict__ b,
                                                     const float* __restrict__ c,
                                                     const float* __restrict__ d,
                                                     _Float16* __restrict__ oa,
                                                     _Float16* __restrict__ ob,
                                                     _Float16* __restrict__ oc,
                                                     _Float16* __restrict__ od, int n) {
  const float* in = blockIdx.y == 0 ? a : blockIdx.y == 1 ? b : blockIdx.y == 2 ? c : d;
  _Float16* out = blockIdx.y == 0 ? oa : blockIdx.y == 1 ? ob : blockIdx.y == 2 ? oc : od;
  int i = (blockIdx.x * 256 + threadIdx.x) * 4;
  if (i < n) {
    float4 v = *reinterpret_cast<const float4*>(in + i);
    h4 o = {(_Float16)v.x, (_Float16)v.y, (_Float16)v.z, (_Float16)v.w};
    *reinterpret_cast<h4*>(out + i) = o;
  }
}

// ---------------- GEMM core: out[m][n] = sum_k A[m][k]*W[n][k] + bias[n] ----
// 128x128 tile, BK=64, 4 waves, 16x16x32 f16 MFMA, global_load_lds w16 with
// XOR swizzle (linear LDS dest + pre-swizzled global source + swizzled read).
template <int OUTF32>
__device__ __forceinline__ void gemm_body(const _Float16* __restrict__ A,
                                          const _Float16* __restrict__ W,
                                          const float* __restrict__ bias,
                                          void* __restrict__ out, char* smem) {
  char* la = smem;
  char* lb = smem + 16384;
  const int t = threadIdx.x;
  const int lane = t & 63;
  const int w = t >> 6;
  const int g = lane >> 4, r16 = lane & 15;
  const int wr = (w >> 1) * 64, wc = (w & 1) * 64;
  const int m0 = blockIdx.x * 128, n0 = blockIdx.y * 128;
  const int p_in_wave = (w << 10) + (lane << 4);

  const char* Ab = (const char*)A;
  const char* Wb = (const char*)W;

  f4 acc[4][4] = {};

  for (int kt = 0; kt < EMBED; kt += 64) {
#pragma unroll
    for (int c = 0; c < 4; c++) {
      int p0 = c * 4096 + p_in_wave;
      int row = p0 >> 7;
      int scol = (p0 & 127) ^ ((row & 7) << 4);
      GLD(Ab + ((size_t)(m0 + row) * EMBED + kt) * 2 + scol, la + c * 4096 + (w << 10));
      GLD(Wb + ((size_t)(n0 + row) * EMBED + kt) * 2 + scol, lb + c * 4096 + (w << 10));
    }
    __syncthreads();
    const int sw = (r16 & 7) << 4;
#pragma unroll
    for (int kk = 0; kk < 2; kk++) {
      h8 af[4], bf[4];
#pragma unroll
      for (int m = 0; m < 4; m++)
        af[m] = *(const h8*)(la + (wr + m * 16 + r16) * 128 + ((kk * 64 + 16 * g) ^ sw));
#pragma unroll
      for (int n = 0; n < 4; n++)
        bf[n] = *(const h8*)(lb + (wc + n * 16 + r16) * 128 + ((kk * 64 + 16 * g) ^ sw));
#pragma unroll
      for (int m = 0; m < 4; m++)
#pragma unroll
        for (int n = 0; n < 4; n++)
          acc[m][n] = __builtin_amdgcn_mfma_f32_16x16x32_f16(af[m], bf[n], acc[m][n], 0, 0, 0);
    }
    __syncthreads();
  }

#pragma unroll
  for (int n = 0; n < 4; n++) {
    int gc = n0 + wc + n * 16 + r16;
    float bv = bias[gc];
#pragma unroll
    for (int m = 0; m < 4; m++) {
#pragma unroll
      for (int r = 0; r < 4; r++) {
        int gr = m0 + wr + m * 16 + 4 * g + r;
        float vv = acc[m][n][r] + bv;
        if (OUTF32)
          reinterpret_cast<float*>(out)[(size_t)gr * EMBED + gc] = vv;
        else
          reinterpret_cast<_Float16*>(out)[(size_t)gr * EMBED + gc] = (_Float16)vv;
      }
    }
  }
}

// QKV projections in one launch: blockIdx.z selects (A, W, bias, out).
__global__ __launch_bounds__(256, 2) void gemm_qkv(const _Float16* qh, const _Float16* kh,
                                                   const _Float16* vh, const _Float16* wq,
                                                   const _Float16* wk, const _Float16* wv,
                                                   const float* bq, const float* bk,
                                                   const float* bv, _Float16* Q, _Float16* K,
                                                   _Float16* V) {
  __shared__ char smem[32768];
  const int z = blockIdx.z;
  const _Float16* A = z == 0 ? qh : z == 1 ? kh : vh;
  const _Float16* W = z == 0 ? wq : z == 1 ? wk : wv;
  const float* bias = z == 0 ? bq : z == 1 ? bk : bv;
  _Float16* out = z == 0 ? Q : z == 1 ? K : V;
  gemm_body<0>(A, W, bias, (void*)out, smem);
}

__global__ __launch_bounds__(256, 2) void gemm_out(const _Float16* __restrict__ A,
                                                   const _Float16* __restrict__ W,
                                                   const float* __restrict__ bias,
                                                   float* __restrict__ out) {
  __shared__ char smem[32768];
  gemm_body<1>(A, W, bias, (void*)out, smem);
}

// ---------------- V transpose: [B,S,H*64] -> Vt2[B*H][64][2048] -------------
// Key-permuted within each 32-key chunk: key = hf*16 + 4g + j  ->  pos =
// g*8 + hf*4 + j, so pass2's PV B-frag is one contiguous ds_read_b128.
// Writes stay 8B-granule, full-line covering (round-8 scatter lesson).
__global__ __launch_bounds__(256) void transpose_v(const _Float16* __restrict__ Vp,
                                                   _Float16* __restrict__ Vt) {
  __shared__ _Float16 tile[64][72];
  const int s0 = blockIdx.x * 64;
  const int bh = blockIdx.y;
  const int b = bh >> 4, h = bh & 15;
  const int t = threadIdx.x;
#pragma unroll
  for (int it = 0; it < 2; it++) {
    int c = t + it * 256;
    int r = c >> 3, c8 = (c & 7) * 8;
    *reinterpret_cast<float4*>(&tile[r][c8]) =
        *reinterpret_cast<const float4*>(Vp + ((size_t)b * SS + s0 + r) * EMBED + h * HD + c8);
  }
  __syncthreads();
#pragma unroll
  for (int it = 0; it < 2; it++) {
    int c = t + it * 256;
    int d = c >> 3, s8 = (c & 7) * 8;
    int s32 = s8 & 31;
    int hf = s32 >> 4;
    int g0 = (s32 & 8) ? 2 : 0;
    h4 lo = {tile[s8 + 0][d], tile[s8 + 1][d], tile[s8 + 2][d], tile[s8 + 3][d]};
    h4 hi = {tile[s8 + 4][d], tile[s8 + 5][d], tile[s8 + 6][d], tile[s8 + 7][d]};
    _Float16* base = Vt + ((size_t)bh * HD + d) * SS + s0 + (s8 & ~31);
    *reinterpret_cast<h4*>(base + g0 * 8 + hf * 4) = lo;
    *reinterpret_cast<h4*>(base + (g0 + 1) * 8 + hf * 4) = hi;
  }
}

// ---------------- attention pass 1: lgr = -log2(sum_k exp2(S*CC)) ----------
// Grid: (SS/128, B*H). Block 256 = 4 waves. Wave w owns q rows
// {qt*128+16w+r16, +64}: TWO q-tiles register-blocked — each K fragment read
// feeds 2 MFMAs. K double-buffered (16 KB LDS), one barrier/iter.
__global__ __launch_bounds__(256, 4) void attn_pass1(const _Float16* __restrict__ Q,
                                                     const _Float16* __restrict__ K,
                                                     float* __restrict__ lbuf) {
  __shared__ char smem[16384];
  const int t = threadIdx.x;
  const int lane = t & 63;
  const int w = t >> 6;
  const int g = lane >> 4, r16 = lane & 15;
  const int qt = blockIdx.x;
  const int bh = blockIdx.y;
  const int b = bh >> 4, h = bh & 15;
  const int q0 = qt * 128 + w * 16;   // wave's first q-tile row; second = +64
  const int p_in_wave = (w << 10) + (lane << 4);
  const int sw = (r16 & 7) << 4;
  const float CC = 0.1803368801f;  // (1/sqrt(64)) * log2(e)

  const char* kbase = (const char*)K + ((size_t)b * SS * EMBED + h * HD) * 2;

  int srow[2], scol[2];
#pragma unroll
  for (int c = 0; c < 2; c++) {
    int p0 = c * 4096 + p_in_wave;
    srow[c] = p0 >> 7;
    scol[c] = (p0 & 127) ^ ((srow[c] & 7) << 4);
  }

#define STAGE_K1(boff, kb)                                                             \
  {                                                                                    \
    _Pragma("unroll") for (int c = 0; c < 2; c++)                                      \
        GLD(kbase + (size_t)((kb) * 64 + srow[c]) * 2048 + scol[c],                    \
            smem + (boff) + c * 4096 + (w << 10));                                     \
  }

  h8 qf0[2], qf1[2];
  {
    const _Float16* qp0 = Q + ((size_t)b * SS + q0 + r16) * EMBED + h * HD;
    const _Float16* qp1 = Q + ((size_t)b * SS + q0 + 64 + r16) * EMBED + h * HD;
#pragma unroll
    for (int kk = 0; kk < 2; kk++) {
      qf0[kk] = *reinterpret_cast<const h8*>(qp0 + kk * 32 + 8 * g);
      qf1[kk] = *reinterpret_cast<const h8*>(qp1 + kk * 32 + 8 * g);
    }
  }

  float l0 = 0.0f, l1 = 0.0f;
  STAGE_K1(0, 0);
  __syncthreads();
  for (int kb = 0; kb < 32; kb++) {
    const char* cur = smem + (kb & 1) * 8192;
    if (kb < 31) STAGE_K1(((kb + 1) & 1) * 8192, kb + 1);
    float s0 = 0.f, s1 = 0.f;
    __builtin_amdgcn_s_setprio(1);
#pragma unroll
    for (int kf = 0; kf < 4; kf++) {
      f4 sfa = {0.f, 0.f, 0.f, 0.f}, sfb = {0.f, 0.f, 0.f, 0.f};
#pragma unroll
      for (int kk = 0; kk < 2; kk++) {
        h8 af = *(const h8*)(cur + (kf * 16 + r16) * 128 + ((kk * 64 + 16 * g) ^ sw));
        sfa = __builtin_amdgcn_mfma_f32_16x16x32_f16(af, qf0[kk], sfa, 0, 0, 0);
        sfb = __builtin_amdgcn_mfma_f32_16x16x32_f16(af, qf1[kk], sfb, 0, 0, 0);
      }
#pragma unroll
      for (int r = 0; r < 4; r++) {
        s0 += fexp2(sfa[r] * CC);
        s1 += fexp2(sfb[r] * CC);
      }
    }
    __builtin_amdgcn_s_setprio(0);
    s0 += __shfl_xor(s0, 16, 64);
    s0 += __shfl_xor(s0, 32, 64);
    s1 += __shfl_xor(s1, 16, 64);
    s1 += __shfl_xor(s1, 32, 64);
    l0 += s0;
    l1 += s1;
    __syncthreads();
  }
  if (lane < 16) {
    lbuf[(size_t)bh * SS + q0 + lane] = -__log2f(l0);
    lbuf[(size_t)bh * SS + q0 + 64 + lane] = -__log2f(l1);
  }
#undef STAGE_K1
}

// ---------------- attention pass 2: attn write + PV --------------------------
// Same q-blocking x2. K and Vt2 double-buffered (32 KB LDS). One V b128 read
// feeds both q-tiles' PV MFMAs. a = exp2(fma(S, CC, lgr)); nontemporal f4
// stores (4 g-lanes cover a full 64B line per instruction).
__global__ __launch_bounds__(256, 3) void attn_pass2(const _Float16* __restrict__ Q,
                                                     const _Float16* __restrict__ K,
                                                     const _Float16* __restrict__ Vt,
                                                     const float* __restrict__ lbuf,
                                                     float* __restrict__ attn_out,
                                                     _Float16* __restrict__ Oh) {
  __shared__ char smem[32768];
  const int t = threadIdx.x;
  const int lane = t & 63;
  const int w = t >> 6;
  const int g = lane >> 4, r16 = lane & 15;
  const int qt = blockIdx.x;
  const int bh = blockIdx.y;
  const int b = bh >> 4, h = bh & 15;
  const int q0 = qt * 128 + w * 16;
  const int p_in_wave = (w << 10) + (lane << 4);
  const int sw = (r16 & 7) << 4;
  const float CC = 0.1803368801f;

  const char* kbase = (const char*)K + ((size_t)b * SS * EMBED + h * HD) * 2;
  const char* vtbase = (const char*)Vt + (size_t)bh * HD * SS * 2;

  int srow[2], scol[2];
#pragma unroll
  for (int c = 0; c < 2; c++) {
    int p0 = c * 4096 + p_in_wave;
    srow[c] = p0 >> 7;
    scol[c] = (p0 & 127) ^ ((srow[c] & 7) << 4);
  }

#define STAGE_K2(boff, kb)                                                             \
  {                                                                                    \
    _Pragma("unroll") for (int c = 0; c < 2; c++)                                      \
        GLD(kbase + (size_t)((kb) * 64 + srow[c]) * 2048 + scol[c],                    \
            smem + (boff) + c * 4096 + (w << 10));                                     \
  }
#define STAGE_V2(boff, kb)                                                             \
  {                                                                                    \
    _Pragma("unroll") for (int c = 0; c < 2; c++)                                      \
        GLD(vtbase + (size_t)srow[c] * 4096 + (kb) * 128 + scol[c],                    \
            smem + (boff) + c * 4096 + (w << 10));                                     \
  }

  h8 qf0[2], qf1[2];
  {
    const _Float16* qp0 = Q + ((size_t)b * SS + q0 + r16) * EMBED + h * HD;
    const _Float16* qp1 = Q + ((size_t)b * SS + q0 + 64 + r16) * EMBED + h * HD;
#pragma unroll
    for (int kk = 0; kk < 2; kk++) {
      qf0[kk] = *reinterpret_cast<const h8*>(qp0 + kk * 32 + 8 * g);
      qf1[kk] = *reinterpret_cast<const h8*>(qp1 + kk * 32 + 8 * g);
    }
  }

  const float lg0 = lbuf[(size_t)bh * SS + q0 + r16];
  const float lg1 = lbuf[(size_t)bh * SS + q0 + 64 + r16];

  f4 oacc0[4] = {}, oacc1[4] = {};
  float* arow0 = attn_out + ((size_t)bh * SS + q0 + r16) * SS;
  float* arow1 = attn_out + ((size_t)bh * SS + q0 + 64 + r16) * SS;

  STAGE_K2(0, 0);
  STAGE_V2(16384, 0);
  __syncthreads();
  for (int kb = 0; kb < 32; kb++) {
    const char* ck = smem + (kb & 1) * 8192;
    const char* cv = smem + 16384 + (kb & 1) * 8192;
    if (kb < 31) {
      STAGE_K2(((kb + 1) & 1) * 8192, kb + 1);
      STAGE_V2(16384 + ((kb + 1) & 1) * 8192, kb + 1);
    }
    h4 pa0[4], pa1[4];
    __builtin_amdgcn_s_setprio(1);
#pragma unroll
    for (int kf = 0; kf < 4; kf++) {
      f4 sfa = {0.f, 0.f, 0.f, 0.f}, sfb = {0.f, 0.f, 0.f, 0.f};
#pragma unroll
      for (int kk = 0; kk < 2; kk++) {
        h8 af = *(const h8*)(ck + (kf * 16 + r16) * 128 + ((kk * 64 + 16 * g) ^ sw));
        sfa = __builtin_amdgcn_mfma_f32_16x16x32_f16(af, qf0[kk], sfa, 0, 0, 0);
        sfb = __builtin_amdgcn_mfma_f32_16x16x32_f16(af, qf1[kk], sfb, 0, 0, 0);
      }
      __builtin_amdgcn_s_setprio(0);
      float a0 = fexp2(fmaf(sfa[0], CC, lg0));
      float a1 = fexp2(fmaf(sfa[1], CC, lg0));
      float a2 = fexp2(fmaf(sfa[2], CC, lg0));
      float a3 = fexp2(fmaf(sfa[3], CC, lg0));
      f4 st0 = {a0, a1, a2, a3};
      __builtin_nontemporal_store(st0, reinterpret_cast<f4*>(arow0 + kb * 64 + kf * 16 + 4 * g));
      pa0[kf] = h4{(_Float16)a0, (_Float16)a1, (_Float16)a2, (_Float16)a3};
      float b0 = fexp2(fmaf(sfb[0], CC, lg1));
      float b1 = fexp2(fmaf(sfb[1], CC, lg1));
      float b2 = fexp2(fmaf(sfb[2], CC, lg1));
      float b3 = fexp2(fmaf(sfb[3], CC, lg1));
      f4 st1 = {b0, b1, b2, b3};
      __builtin_nontemporal_store(st1, reinterpret_cast<f4*>(arow1 + kb * 64 + kf * 16 + 4 * g));
      pa1[kf] = h4{(_Float16)b0, (_Float16)b1, (_Float16)b2, (_Float16)b3};
      __builtin_amdgcn_s_setprio(1);
    }
    // PV: A k-map j<4 -> 4g+j, j>=4 -> 16+4g+j; Vt2 permuted so B-frag is
    // one b128 (halves kf2*32 + g*8 .. +8). One V read serves both q-tiles.
#pragma unroll
    for (int kf2 = 0; kf2 < 2; kf2++) {
      h8 paA = __builtin_shufflevector(pa0[2 * kf2], pa0[2 * kf2 + 1], 0, 1, 2, 3, 4, 5, 6, 7);
      h8 paB = __builtin_shufflevector(pa1[2 * kf2], pa1[2 * kf2 + 1], 0, 1, 2, 3, 4, 5, 6, 7);
#pragma unroll
      for (int dt = 0; dt < 4; dt++) {
        h8 bf8 = *(const h8*)(cv + (dt * 16 + r16) * 128 + ((kf2 * 64 + 16 * g) ^ sw));
        oacc0[dt] = __builtin_amdgcn_mfma_f32_16x16x32_f16(paA, bf8, oacc0[dt], 0, 0, 0);
        oacc1[dt] = __builtin_amdgcn_mfma_f32_16x16x32_f16(paB, bf8, oacc1[dt], 0, 0, 0);
      }
    }
    __builtin_amdgcn_s_setprio(0);
    __syncthreads();
  }

#pragma unroll
  for (int dt = 0; dt < 4; dt++) {
#pragma unroll
    for (int r = 0; r < 4; r++) {
      Oh[((size_t)b * SS + q0 + 4 * g + r) * EMBED + h * HD + dt * 16 + r16] =
          (_Float16)oacc0[dt][r];
      Oh[((size_t)b * SS + q0 + 64 + 4 * g + r) * EMBED + h * HD + dt * 16 + r16] =
          (_Float16)oacc1[dt][r];
    }
  }
#undef STAGE_K2
#undef STAGE_V2
}

// ---------------------------------------------------------------------------
extern "C" void kernel_launch(void* const* d_in, const int* in_sizes, int n_in,
                              void* d_out, int out_size, void* d_ws, size_t ws_size,
                              hipStream_t stream) {
  const float* q  = (const float*)d_in[0];
  const float* k  = (const float*)d_in[1];
  const float* v  = (const float*)d_in[2];
  const float* Wq = (const float*)d_in[3];
  const float* bq = (const float*)d_in[4];
  const float* Wk = (const float*)d_in[5];
  const float* bk = (const float*)d_in[6];
  const float* Wv = (const float*)d_in[7];
  const float* bv = (const float*)d_in[8];
  const float* Wo = (const float*)d_in[9];
  const float* bo = (const float*)d_in[10];

  const size_t NW = (size_t)EMBED * EMBED;   // 1,048,576
  const size_t NX = (size_t)MROWS * EMBED;   // 8,388,608

  if (ws_size < (4 * NW + 6 * NX) * sizeof(_Float16)) return;  // loud failure
  _Float16* ws  = (_Float16*)d_ws;
  _Float16* wqh = ws;
  _Float16* wkh = wqh + NW;
  _Float16* wvh = wkh + NW;
  _Float16* woh = wvh + NW;
  _Float16* qh  = woh + NW;
  _Float16* kh  = qh + NX;
  _Float16* vh  = kh + NX;
  _Float16* Qh  = vh + NX;
  _Float16* Kh  = Qh + NX;
  _Float16* Vph = Kh + NX;
  _Float16* Vt2 = qh;           // alias: qh dead after gemm_qkv
  _Float16* OhA = kh;           // alias: kh dead after gemm_qkv
  float* lbuf   = (float*)vh;   // alias: vh dead after gemm_qkv (needs 512 KB)

  float* xout = (float*)d_out;
  float* attn = xout + NX;

  cast3_f32_f16<<<dim3((NX / 4 + 255) / 256, 3), dim3(256), 0, stream>>>(q, k, v, qh, kh, vh,
                                                                         (int)NX);
  cast4_f32_f16<<<dim3((NW / 4 + 255) / 256, 4), dim3(256), 0, stream>>>(
      Wq, Wk, Wv, Wo, wqh, wkh, wvh, woh, (int)NW);

  dim3 ggrid(MROWS / 128, EMBED / 128), gblk(256);
  gemm_qkv<<<dim3(MROWS / 128, EMBED / 128, 3), gblk, 0, stream>>>(qh, kh, vh, wqh, wkh, wvh,
                                                                   bq, bk, bv, Qh, Kh, Vph);

  transpose_v<<<dim3(SS / 64, BB * HEADS), dim3(256), 0, stream>>>(Vph, Vt2);

  attn_pass1<<<dim3(SS / 128, BB * HEADS), dim3(256), 0, stream>>>(Qh, Kh, lbuf);

  attn_pass2<<<dim3(SS / 128, BB * HEADS), dim3(256), 0, stream>>>(Qh, Kh, Vt2, lbuf, attn,
                                                                   OhA);

  gemm_out<<<ggrid, gblk, 0, stream>>>(OhA, woh, bo, xout);
}

// Round 11
// 507.829 us; speedup vs baseline: 1.1257x; 1.1257x over previous
//
#include <hip/hip_runtime.h>
#include <hip/hip_bf16.h>

// ---------------------------------------------------------------------------
// CustomMultiheadAttention on MI355X (gfx950)
//   x = softmax((q Wq^T + bq)(k Wk^T + bk)^T / sqrt(64)) (v Wv^T + bv) Wo^T + bo
// Outputs (concat, fp32): x [4,2048,1024], attn [4,16,2048,2048]
//
// Round-11: revert to round-5's best-known attn geometry (single fused
// kernel, 64 q-rows/block, 4 waves, dbuf, one barrier/iter, setprio).
// Keep only strictly-local wins: no-max softmax (shift-invariant, scores
// ~N(0,1), validated absmax) + fma-folded normalization; key-permuted Vt2
// so the PV B-frag is a single ds_read_b128.
// ---------------------------------------------------------------------------

typedef _Float16 h4 __attribute__((ext_vector_type(4)));
typedef _Float16 h8 __attribute__((ext_vector_type(8)));
typedef float f4 __attribute__((ext_vector_type(4)));

#define EMBED 1024
#define HEADS 16
#define HD 64
#define BB 4
#define SS 2048
#define MROWS (BB * SS) // 8192

#define GLD(src, dst)                                                                  \
  __builtin_amdgcn_global_load_lds((const __attribute__((address_space(1))) void*)(src), \
                                   (__attribute__((address_space(3))) void*)(dst), 16, 0, 0)

__device__ inline float fexp2(float x) {
  float r;
  asm("v_exp_f32 %0, %1" : "=v"(r) : "v"(x));
  return r;
}

// ---------------- fused casts fp32 -> fp16 ----------------
__global__ __launch_bounds__(256) void cast3_f32_f16(const float* __restrict__ a,
                                                     const float* __restrict__ b,
                                                     const float* __restrict__ c,
                                                     _Float16* __restrict__ oa,
                                                     _Float16* __restrict__ ob,
                                                     _Float16* __restrict__ oc, int n) {
  const float* in = blockIdx.y == 0 ? a : blockIdx.y == 1 ? b : c;
  _Float16* out = blockIdx.y == 0 ? oa : blockIdx.y == 1 ? ob : oc;
  int i = (blockIdx.x * 256 + threadIdx.x) * 4;
  if (i < n) {
    float4 v = *reinterpret_cast<const float4*>(in + i);
    h4 o = {(_Float16)v.x, (_Float16)v.y, (_Float16)v.z, (_Float16)v.w};
    *reinterpret_cast<h4*>(out + i) = o;
  }
}

__global__ __launch_bounds__(256) void cast4_f32_f16(const float* __restrict__ a,
                                                     const float* __restrict__ b,
                                                     const float* __restrict__ c,
                                                     const float* __restrict__ d,
                                                     _Float16* __restrict__ oa,
                                                     _Float16* __restrict__ ob,
                                                     _Float16* __restrict__ oc,
                                                     _Float16* __restrict__ od, int n) {
  const float* in = blockIdx.y == 0 ? a : blockIdx.y == 1 ? b : blockIdx.y == 2 ? c : d;
  _Float16* out = blockIdx.y == 0 ? oa : blockIdx.y == 1 ? ob : blockIdx.y == 2 ? oc : od;
  int i = (blockIdx.x * 256 + threadIdx.x) * 4;
  if (i < n) {
    float4 v = *reinterpret_cast<const float4*>(in + i);
    h4 o = {(_Float16)v.x, (_Float16)v.y, (_Float16)v.z, (_Float16)v.w};
    *reinterpret_cast<h4*>(out + i) = o;
  }
}

// ---------------- GEMM core: out[m][n] = sum_k A[m][k]*W[n][k] + bias[n] ----
// 128x128 tile, BK=64, 4 waves, 16x16x32 f16 MFMA, global_load_lds w16 with
// XOR swizzle (linear LDS dest + pre-swizzled global source + swizzled read).
template <int OUTF32>
__device__ __forceinline__ void gemm_body(const _Float16* __restrict__ A,
                                          const _Float16* __restrict__ W,
                                          const float* __restrict__ bias,
                                          void* __restrict__ out, char* smem) {
  char* la = smem;
  char* lb = smem + 16384;
  const int t = threadIdx.x;
  const int lane = t & 63;
  const int w = t >> 6;
  const int g = lane >> 4, r16 = lane & 15;
  const int wr = (w >> 1) * 64, wc = (w & 1) * 64;
  const int m0 = blockIdx.x * 128, n0 = blockIdx.y * 128;
  const int p_in_wave = (w << 10) + (lane << 4);

  const char* Ab = (const char*)A;
  const char* Wb = (const char*)W;

  f4 acc[4][4] = {};

  for (int kt = 0; kt < EMBED; kt += 64) {
#pragma unroll
    for (int c = 0; c < 4; c++) {
      int p0 = c * 4096 + p_in_wave;
      int row = p0 >> 7;
      int scol = (p0 & 127) ^ ((row & 7) << 4);
      GLD(Ab + ((size_t)(m0 + row) * EMBED + kt) * 2 + scol, la + c * 4096 + (w << 10));
      GLD(Wb + ((size_t)(n0 + row) * EMBED + kt) * 2 + scol, lb + c * 4096 + (w << 10));
    }
    __syncthreads();
    const int sw = (r16 & 7) << 4;
#pragma unroll
    for (int kk = 0; kk < 2; kk++) {
      h8 af[4], bf[4];
#pragma unroll
      for (int m = 0; m < 4; m++)
        af[m] = *(const h8*)(la + (wr + m * 16 + r16) * 128 + ((kk * 64 + 16 * g) ^ sw));
#pragma unroll
      for (int n = 0; n < 4; n++)
        bf[n] = *(const h8*)(lb + (wc + n * 16 + r16) * 128 + ((kk * 64 + 16 * g) ^ sw));
#pragma unroll
      for (int m = 0; m < 4; m++)
#pragma unroll
        for (int n = 0; n < 4; n++)
          acc[m][n] = __builtin_amdgcn_mfma_f32_16x16x32_f16(af[m], bf[n], acc[m][n], 0, 0, 0);
    }
    __syncthreads();
  }

#pragma unroll
  for (int n = 0; n < 4; n++) {
    int gc = n0 + wc + n * 16 + r16;
    float bv = bias[gc];
#pragma unroll
    for (int m = 0; m < 4; m++) {
#pragma unroll
      for (int r = 0; r < 4; r++) {
        int gr = m0 + wr + m * 16 + 4 * g + r;
        float vv = acc[m][n][r] + bv;
        if (OUTF32)
          reinterpret_cast<float*>(out)[(size_t)gr * EMBED + gc] = vv;
        else
          reinterpret_cast<_Float16*>(out)[(size_t)gr * EMBED + gc] = (_Float16)vv;
      }
    }
  }
}

// QKV projections in one launch: blockIdx.z selects (A, W, bias, out).
__global__ __launch_bounds__(256, 2) void gemm_qkv(const _Float16* qh, const _Float16* kh,
                                                   const _Float16* vh, const _Float16* wq,
                                                   const _Float16* wk, const _Float16* wv,
                                                   const float* bq, const float* bk,
                                                   const float* bv, _Float16* Q, _Float16* K,
                                                   _Float16* V) {
  __shared__ char smem[32768];
  const int z = blockIdx.z;
  const _Float16* A = z == 0 ? qh : z == 1 ? kh : vh;
  const _Float16* W = z == 0 ? wq : z == 1 ? wk : wv;
  const float* bias = z == 0 ? bq : z == 1 ? bk : bv;
  _Float16* out = z == 0 ? Q : z == 1 ? K : V;
  gemm_body<0>(A, W, bias, (void*)out, smem);
}

__global__ __launch_bounds__(256, 2) void gemm_out(const _Float16* __restrict__ A,
                                                   const _Float16* __restrict__ W,
                                                   const float* __restrict__ bias,
                                                   float* __restrict__ out) {
  __shared__ char smem[32768];
  gemm_body<1>(A, W, bias, (void*)out, smem);
}

// ---------------- V transpose: [B,S,H*64] -> Vt2[B*H][64][2048] -------------
// Key-permuted within each 32-key chunk: key = hf*16 + 4g + j  ->  pos =
// g*8 + hf*4 + j, so the PV B-frag is one contiguous ds_read_b128.
// Writes stay 8B-granule, full-line covering (round-8 scatter lesson).
__global__ __launch_bounds__(256) void transpose_v(const _Float16* __restrict__ Vp,
                                                   _Float16* __restrict__ Vt) {
  __shared__ _Float16 tile[64][72];
  const int s0 = blockIdx.x * 64;
  const int bh = blockIdx.y;
  const int b = bh >> 4, h = bh & 15;
  const int t = threadIdx.x;
#pragma unroll
  for (int it = 0; it < 2; it++) {
    int c = t + it * 256;
    int r = c >> 3, c8 = (c & 7) * 8;
    *reinterpret_cast<float4*>(&tile[r][c8]) =
        *reinterpret_cast<const float4*>(Vp + ((size_t)b * SS + s0 + r) * EMBED + h * HD + c8);
  }
  __syncthreads();
#pragma unroll
  for (int it = 0; it < 2; it++) {
    int c = t + it * 256;
    int d = c >> 3, s8 = (c & 7) * 8;
    int s32 = s8 & 31;
    int hf = s32 >> 4;
    int g0 = (s32 & 8) ? 2 : 0;
    h4 lo = {tile[s8 + 0][d], tile[s8 + 1][d], tile[s8 + 2][d], tile[s8 + 3][d]};
    h4 hi = {tile[s8 + 4][d], tile[s8 + 5][d], tile[s8 + 6][d], tile[s8 + 7][d]};
    _Float16* base = Vt + ((size_t)bh * HD + d) * SS + s0 + (s8 & ~31);
    *reinterpret_cast<h4*>(base + g0 * 8 + hf * 4) = lo;
    *reinterpret_cast<h4*>(base + (g0 + 1) * 8 + hf * 4) = hi;
  }
}

// ---------------- fused attention (round-5 geometry) -------------------------
// Grid: (SS/64, B*H). Block 256 = 4 waves; wave w owns q rows [qt*64+16w,+16).
// Swapped QK^T (16x16x32): lane holds S[key=4g+r][q=r16]. No max subtraction
// (scores ~N(0,1), shift-invariant). Pass 1: l = sum exp2(S*CC). Pass 2:
// recompute S, a = exp2(fma(S,CC,-log2 l)) -> nontemporal f4 store + PV.
// K (and V in pass 2) double-buffered; ONE barrier per iteration.
__global__ __launch_bounds__(256, 2) void attn_fused(const _Float16* __restrict__ Q,
                                                     const _Float16* __restrict__ K,
                                                     const _Float16* __restrict__ Vt,
                                                     float* __restrict__ attn_out,
                                                     _Float16* __restrict__ Oh) {
  __shared__ char smem[32768];
  const int t = threadIdx.x;
  const int lane = t & 63;
  const int w = t >> 6;
  const int g = lane >> 4, r16 = lane & 15;
  const int qt = blockIdx.x;
  const int bh = blockIdx.y;
  const int b = bh >> 4, h = bh & 15;
  const int qrow = qt * 64 + w * 16 + r16;
  const int p_in_wave = (w << 10) + (lane << 4);
  const int sw = (r16 & 7) << 4;

  const float CC = 0.1803368801f;  // (1/sqrt(64)) * log2(e)

  const char* kbase = (const char*)K + ((size_t)b * SS * EMBED + h * HD) * 2;
  const char* vtbase = (const char*)Vt + (size_t)bh * HD * SS * 2;

  int srow[2], scol[2];
#pragma unroll
  for (int c = 0; c < 2; c++) {
    int p0 = c * 4096 + p_in_wave;
    srow[c] = p0 >> 7;
    scol[c] = (p0 & 127) ^ ((srow[c] & 7) << 4);
  }

  // K buffers at smem+{0,8192}, V buffers at smem+{16384,24576}
#define STAGE_K(boff, kb)                                                              \
  {                                                                                    \
    _Pragma("unroll") for (int c = 0; c < 2; c++)                                      \
        GLD(kbase + (size_t)((kb) * 64 + srow[c]) * 2048 + scol[c],                    \
            smem + (boff) + c * 4096 + (w << 10));                                     \
  }
#define STAGE_V(boff, kb)                                                              \
  {                                                                                    \
    _Pragma("unroll") for (int c = 0; c < 2; c++)                                      \
        GLD(vtbase + (size_t)srow[c] * 4096 + (kb) * 128 + scol[c],                    \
            smem + (boff) + c * 4096 + (w << 10));                                     \
  }

  // hoist Q fragments (B-operand: col=q=r16, k = kk*32 + 8g + j)
  h8 qf[2];
  const _Float16* qptr = Q + ((size_t)b * SS + qrow) * EMBED + h * HD;
#pragma unroll
  for (int kk = 0; kk < 2; kk++)
    qf[kk] = *reinterpret_cast<const h8*>(qptr + kk * 32 + 8 * g);

  // ---- pass 1: l = sum over keys of exp2(S*CC) ----
  float l_run = 0.0f;
  STAGE_K(0, 0);
  __syncthreads();
  for (int kb = 0; kb < 32; kb++) {
    const char* cur = smem + (kb & 1) * 8192;
    if (kb < 31) STAGE_K(((kb + 1) & 1) * 8192, kb + 1);
    float s = 0.f;
    __builtin_amdgcn_s_setprio(1);
#pragma unroll
    for (int kf = 0; kf < 4; kf++) {
      f4 sf = {0.f, 0.f, 0.f, 0.f};
#pragma unroll
      for (int kk = 0; kk < 2; kk++) {
        h8 af = *(const h8*)(cur + (kf * 16 + r16) * 128 + ((kk * 64 + 16 * g) ^ sw));
        sf = __builtin_amdgcn_mfma_f32_16x16x32_f16(af, qf[kk], sf, 0, 0, 0);
      }
#pragma unroll
      for (int r = 0; r < 4; r++) s += fexp2(sf[r] * CC);
    }
    __builtin_amdgcn_s_setprio(0);
    s += __shfl_xor(s, 16, 64);
    s += __shfl_xor(s, 32, 64);
    l_run += s;
    __syncthreads();
  }
  const float lgr = -__log2f(l_run);

  // ---- pass 2: recompute, write normalized attn, accumulate PV ----
  f4 oacc[4] = {};
  float* arow = attn_out + ((size_t)bh * SS + qrow) * SS;

  STAGE_K(0, 0);
  STAGE_V(16384, 0);
  __syncthreads();
  for (int kb = 0; kb < 32; kb++) {
    const char* ck = smem + (kb & 1) * 8192;
    const char* cv = smem + 16384 + (kb & 1) * 8192;
    if (kb < 31) {
      STAGE_K(((kb + 1) & 1) * 8192, kb + 1);
      STAGE_V(16384 + ((kb + 1) & 1) * 8192, kb + 1);
    }
    h4 pa[4];
    __builtin_amdgcn_s_setprio(1);
#pragma unroll
    for (int kf = 0; kf < 4; kf++) {
      f4 sf = {0.f, 0.f, 0.f, 0.f};
#pragma unroll
      for (int kk = 0; kk < 2; kk++) {
        h8 af = *(const h8*)(ck + (kf * 16 + r16) * 128 + ((kk * 64 + 16 * g) ^ sw));
        sf = __builtin_amdgcn_mfma_f32_16x16x32_f16(af, qf[kk], sf, 0, 0, 0);
      }
      __builtin_amdgcn_s_setprio(0);
      float a0 = fexp2(fmaf(sf[0], CC, lgr));
      float a1 = fexp2(fmaf(sf[1], CC, lgr));
      float a2 = fexp2(fmaf(sf[2], CC, lgr));
      float a3 = fexp2(fmaf(sf[3], CC, lgr));
      f4 st = {a0, a1, a2, a3};
      __builtin_nontemporal_store(st, reinterpret_cast<f4*>(arow + kb * 64 + kf * 16 + 4 * g));
      pa[kf] = h4{(_Float16)a0, (_Float16)a1, (_Float16)a2, (_Float16)a3};
      __builtin_amdgcn_s_setprio(1);
    }
    // PV: A k-map j<4 -> 4g+j, j>=4 -> 16+4g+j; Vt2 permuted so B-frag is
    // one b128 (keys kf2*32 + g*8 .. +8, in A's k-order).
#pragma unroll
    for (int kf2 = 0; kf2 < 2; kf2++) {
      h8 pa8 = __builtin_shufflevector(pa[2 * kf2], pa[2 * kf2 + 1], 0, 1, 2, 3, 4, 5, 6, 7);
#pragma unroll
      for (int dt = 0; dt < 4; dt++) {
        h8 bf8 = *(const h8*)(cv + (dt * 16 + r16) * 128 + ((kf2 * 64 + 16 * g) ^ sw));
        oacc[dt] = __builtin_amdgcn_mfma_f32_16x16x32_f16(pa8, bf8, oacc[dt], 0, 0, 0);
      }
    }
    __builtin_amdgcn_s_setprio(0);
    __syncthreads();
  }

  // write O (fp16) to [B,S,EMBED] for the final projection
  const int orow0 = qt * 64 + w * 16;
#pragma unroll
  for (int dt = 0; dt < 4; dt++) {
#pragma unroll
    for (int r = 0; r < 4; r++) {
      Oh[((size_t)b * SS + orow0 + 4 * g + r) * EMBED + h * HD + dt * 16 + r16] =
          (_Float16)oacc[dt][r];
    }
  }
#undef STAGE_K
#undef STAGE_V
}

// ---------------------------------------------------------------------------
extern "C" void kernel_launch(void* const* d_in, const int* in_sizes, int n_in,
                              void* d_out, int out_size, void* d_ws, size_t ws_size,
                              hipStream_t stream) {
  const float* q  = (const float*)d_in[0];
  const float* k  = (const float*)d_in[1];
  const float* v  = (const float*)d_in[2];
  const float* Wq = (const float*)d_in[3];
  const float* bq = (const float*)d_in[4];
  const float* Wk = (const float*)d_in[5];
  const float* bk = (const float*)d_in[6];
  const float* Wv = (const float*)d_in[7];
  const float* bv = (const float*)d_in[8];
  const float* Wo = (const float*)d_in[9];
  const float* bo = (const float*)d_in[10];

  const size_t NW = (size_t)EMBED * EMBED;   // 1,048,576
  const size_t NX = (size_t)MROWS * EMBED;   // 8,388,608

  if (ws_size < (4 * NW + 6 * NX) * sizeof(_Float16)) return;  // loud failure
  _Float16* ws  = (_Float16*)d_ws;
  _Float16* wqh = ws;
  _Float16* wkh = wqh + NW;
  _Float16* wvh = wkh + NW;
  _Float16* woh = wvh + NW;
  _Float16* qh  = woh + NW;
  _Float16* kh  = qh + NX;
  _Float16* vh  = kh + NX;
  _Float16* Qh  = vh + NX;
  _Float16* Kh  = Qh + NX;
  _Float16* Vph = Kh + NX;
  _Float16* Vt2 = qh;   // alias: qh dead after gemm_qkv
  _Float16* OhA = kh;   // alias: kh dead after gemm_qkv

  float* xout = (float*)d_out;
  float* attn = xout + NX;

  cast3_f32_f16<<<dim3((NX / 4 + 255) / 256, 3), dim3(256), 0, stream>>>(q, k, v, qh, kh, vh,
                                                                         (int)NX);
  cast4_f32_f16<<<dim3((NW / 4 + 255) / 256, 4), dim3(256), 0, stream>>>(
      Wq, Wk, Wv, Wo, wqh, wkh, wvh, woh, (int)NW);

  dim3 ggrid(MROWS / 128, EMBED / 128), gblk(256);
  gemm_qkv<<<dim3(MROWS / 128, EMBED / 128, 3), gblk, 0, stream>>>(qh, kh, vh, wqh, wkh, wvh,
                                                                   bq, bk, bv, Qh, Kh, Vph);

  transpose_v<<<dim3(SS / 64, BB * HEADS), dim3(256), 0, stream>>>(Vph, Vt2);

  attn_fused<<<dim3(SS / 64, BB * HEADS), dim3(256), 0, stream>>>(Qh, Kh, Vt2, attn, OhA);

  gemm_out<<<ggrid, gblk, 0, stream>>>(OhA, woh, bo, xout);
}